// Round 10
// baseline (336.104 us; speedup 1.0000x reference)
//
#include <hip/hip_runtime.h>
#include <hip/hip_bf16.h>

#define EPSV 1e-5f

typedef __attribute__((ext_vector_type(8))) short bf16x8;
typedef __attribute__((ext_vector_type(4))) float f32x4;

static __device__ __forceinline__ short f2bf(float f) {
  return __builtin_bit_cast(short, __float2bfloat16(f));
}

// ---------------- custom zero ----------------
__global__ __launch_bounds__(256) void zero2_kernel(
    int4* __restrict__ p1, long long n1,
    int4* __restrict__ p2, long long n2)
{
  const long long stride = (long long)gridDim.x * blockDim.x;
  const int4 z = make_int4(0, 0, 0, 0);
  for (long long i = blockIdx.x * (long long)blockDim.x + threadIdx.x;
       i < n1; i += stride) p1[i] = z;
  for (long long i = blockIdx.x * (long long)blockDim.x + threadIdx.x;
       i < n2; i += stride) p2[i] = z;
}

// ---------------- fused node MFMA + dst histogram ----------------
// Even blocks: node pipeline (1024 virtual blocks). Odd blocks: hist (1024).
// Disjoint inputs -> hist cost hides under node compute.
__global__ __launch_bounds__(256) void node_hist_kernel(
    const float* __restrict__ node_feats, const float* __restrict__ cond,
    const float* __restrict__ W_cond, const float* __restrict__ b_cond,
    const float* __restrict__ W_film, const float* __restrict__ b_film,
    float* __restrict__ h, int N,
    const int* __restrict__ dst, int* __restrict__ cnt, int E)
{
  __shared__ __align__(16) short cond_s[16][264];
  __shared__ __align__(16) short nf_s[16][136];
  __shared__ __align__(16) float gb_s[16][132];
  __shared__ __align__(16) float h_s[16][68];

  const int t = threadIdx.x;

  if (blockIdx.x & 1) {              // ---- hist path ----
    const int vb = (int)(blockIdx.x >> 1);
    const int stride = 1024 * 256;
    for (int e = vb * 256 + t; e < E; e += stride)
      atomicAdd(&cnt[dst[e]], 1);
    return;
  }

  // ---- node path ----
  const int lane = t & 63;
  const int w = t >> 6;
  const int r16 = lane & 15;
  const int kb = lane >> 4;

  const int colc0 = w * 32 + r16;
  const int colc1 = w * 32 + 16 + r16;
  bf16x8 bc[2][8];
#pragma unroll
  for (int ks = 0; ks < 8; ++ks)
#pragma unroll
    for (int j = 0; j < 8; ++j) {
      const int k = ks * 32 + kb * 8 + j;
      bc[0][ks][j] = f2bf(W_cond[k * 128 + colc0]);
      bc[1][ks][j] = f2bf(W_cond[k * 128 + colc1]);
    }
  const int colf = w * 16 + r16;
  bf16x8 bfm[4];
#pragma unroll
  for (int ks = 0; ks < 4; ++ks)
#pragma unroll
    for (int j = 0; j < 8; ++j)
      bfm[ks][j] = f2bf(W_film[(ks * 32 + kb * 8 + j) * 64 + colf]);
  const float bbc0 = b_cond[colc0] + (w < 2 ? 1.0f : 0.0f);
  const float bbc1 = b_cond[colc1] + (w < 2 ? 1.0f : 0.0f);
  const float bbf = b_film[colf];

  const int ntiles = (N + 15) >> 4;
  for (int tile = (int)(blockIdx.x >> 1); tile < ntiles; tile += 1024) {
    const int n0 = tile << 4;
    const int rows = min(16, N - n0);
    {
      const float4* c4 = (const float4*)(cond + (size_t)n0 * 256);
#pragma unroll
      for (int it = 0; it < 4; ++it) {
        const int i = t + it * 256;
        const int row = i >> 6, c = i & 63;
        const float4 v = (row < rows) ? c4[i] : make_float4(0.f, 0.f, 0.f, 0.f);
        short* p = &cond_s[row][c * 4];
        p[0] = f2bf(v.x); p[1] = f2bf(v.y); p[2] = f2bf(v.z); p[3] = f2bf(v.w);
      }
      const float4* n4 = (const float4*)(node_feats + (size_t)n0 * 128);
#pragma unroll
      for (int it = 0; it < 2; ++it) {
        const int i = t + it * 256;
        const int row = i >> 5, c = i & 31;
        const float4 v = (row < rows) ? n4[i] : make_float4(0.f, 0.f, 0.f, 0.f);
        short* p = &nf_s[row][c * 4];
        p[0] = f2bf(v.x); p[1] = f2bf(v.y); p[2] = f2bf(v.z); p[3] = f2bf(v.w);
      }
    }
    __syncthreads();

    f32x4 cg0 = {0.f, 0.f, 0.f, 0.f}, cg1 = {0.f, 0.f, 0.f, 0.f};
#pragma unroll
    for (int ks = 0; ks < 8; ++ks) {
      const bf16x8 a = *(const bf16x8*)&cond_s[r16][ks * 32 + kb * 8];
      cg0 = __builtin_amdgcn_mfma_f32_16x16x32_bf16(a, bc[0][ks], cg0, 0, 0, 0);
      cg1 = __builtin_amdgcn_mfma_f32_16x16x32_bf16(a, bc[1][ks], cg1, 0, 0, 0);
    }
    f32x4 ch = {0.f, 0.f, 0.f, 0.f};
#pragma unroll
    for (int ks = 0; ks < 4; ++ks) {
      const bf16x8 a = *(const bf16x8*)&nf_s[r16][ks * 32 + kb * 8];
      ch = __builtin_amdgcn_mfma_f32_16x16x32_bf16(a, bfm[ks], ch, 0, 0, 0);
    }
#pragma unroll
    for (int j = 0; j < 4; ++j) {
      gb_s[kb * 4 + j][colc0] = cg0[j] + bbc0;
      gb_s[kb * 4 + j][colc1] = cg1[j] + bbc1;
      h_s[kb * 4 + j][colf]   = ch[j] + bbf;
    }
    __syncthreads();

#pragma unroll
    for (int rr = 0; rr < 4; ++rr) {
      const int r = w * 4 + rr;
      const float v = h_s[r][lane];
      float s = v, q = v * v;
#pragma unroll
      for (int off = 1; off < 64; off <<= 1) {
        s += __shfl_xor(s, off, 64);
        q += __shfl_xor(q, off, 64);
      }
      const float mu = s * (1.0f / 64.0f);
      const float var = q * (1.0f / 64.0f) - mu * mu;
      const float hn = (v - mu) * rsqrtf(var + EPSV);
      const float gm = gb_s[r][lane];
      const float bt = gb_s[r][64 + lane];
      if (r < rows)
        h[(size_t)(n0 + r) * 64 + lane] = fmaxf(fmaf(gm, hn, bt), 0.0f);
    }
  }
}

// ---------------- counting-sort scans ----------------
__global__ __launch_bounds__(256) void scan_blocks(
    const int* __restrict__ cnt, int* __restrict__ binst, int* __restrict__ tileoff,
    int* __restrict__ esum, int* __restrict__ tsum, int N)
{
  __shared__ int we[4], wt[4];
  const int t = threadIdx.x, lane = t & 63, w = t >> 6;
  const int i = blockIdx.x * 256 + t;
  const int c  = (i < N) ? cnt[i] : 0;
  const int nt = (c + 15) >> 4;
  int pe = c, pt = nt;
#pragma unroll
  for (int off = 1; off < 64; off <<= 1) {
    const int ae = __shfl_up(pe, off, 64);
    const int at = __shfl_up(pt, off, 64);
    if (lane >= off) { pe += ae; pt += at; }
  }
  if (lane == 63) { we[w] = pe; wt[w] = pt; }
  __syncthreads();
  if (t == 0) {
    int re = 0, rt = 0;
#pragma unroll
    for (int k = 0; k < 4; ++k) { const int a = we[k], b = wt[k]; we[k] = re; wt[k] = rt; re += a; rt += b; }
    esum[blockIdx.x] = re;
    tsum[blockIdx.x] = rt;
  }
  __syncthreads();
  if (i < N) {
    binst[i]   = we[w] + pe - c;
    tileoff[i] = wt[w] + pt - nt;
  }
}

__global__ __launch_bounds__(256) void scan_tops(
    int* __restrict__ esum, int* __restrict__ tsum, int* __restrict__ Tcnt, int NB)
{
  __shared__ int we[4], wt[4];
  const int t = threadIdx.x, lane = t & 63, w = t >> 6;
  const int c  = (t < NB) ? esum[t] : 0;
  const int nt = (t < NB) ? tsum[t] : 0;
  int pe = c, pt = nt;
#pragma unroll
  for (int off = 1; off < 64; off <<= 1) {
    const int ae = __shfl_up(pe, off, 64);
    const int at = __shfl_up(pt, off, 64);
    if (lane >= off) { pe += ae; pt += at; }
  }
  if (lane == 63) { we[w] = pe; wt[w] = pt; }
  __syncthreads();
  if (t == 0) {
    int re = 0, rt = 0;
#pragma unroll
    for (int k = 0; k < 4; ++k) { const int a = we[k], b = wt[k]; we[k] = re; wt[k] = rt; re += a; rt += b; }
    Tcnt[0] = rt;
  }
  __syncthreads();
  if (t < NB) {
    esum[t] = we[w] + pe - c;
    tsum[t] = wt[w] + pt - nt;
  }
}

// scan_apply + emit_tiles fused: all emit inputs are thread-local here.
__global__ __launch_bounds__(256) void scan_apply_emit(
    int* __restrict__ binst, int* __restrict__ tileoff, int* __restrict__ cursor,
    const int* __restrict__ esum, const int* __restrict__ tsum,
    const int* __restrict__ cnt,
    int* __restrict__ tileA, int* __restrict__ tileB, int N)
{
  const int i = blockIdx.x * 256 + threadIdx.x;
  if (i < N) {
    const int b = binst[i] + esum[blockIdx.x];
    binst[i] = b;
    cursor[i] = b;
    const int to = tileoff[i] + tsum[blockIdx.x];
    tileoff[i] = to;
    const int c = cnt[i];
    const int nt = (c + 15) >> 4;
    for (int k = 0; k < nt; ++k) {
      tileA[to + k] = i | (min(16, c - 16 * k) << 20);
      tileB[to + k] = b + 16 * k;
    }
  }
}

// fill: packed per-slot record {src, mirror, ew_bits, 0}
__global__ __launch_bounds__(256) void fill_kernel(
    const int* __restrict__ dst, const int* __restrict__ src,
    const int* __restrict__ mirror, const float* __restrict__ ew,
    int* __restrict__ cursor, int4* __restrict__ rec, int E)
{
  const int stride = gridDim.x * blockDim.x;
  for (int e = blockIdx.x * blockDim.x + threadIdx.x; e < E; e += stride) {
    const int pos = atomicAdd(&cursor[dst[e]], 1);
    rec[pos] = make_int4(src[e], mirror[e], __float_as_int(ew[e]), 0);
  }
}

// ---------------- fused gather-MFMA-accumulate, depth-1 pipeline -------------
// launch_bounds(256,8): cap VGPR at 64 -> 8 waves/SIMD for latency hiding.
// h loads moved AFTER the MFMAs to shorten peak register live range.
__global__ __launch_bounds__(256, 8) void gather_tiles_kernel(
    const float* __restrict__ ef32,
    const int4* __restrict__ rec,
    const int* __restrict__ tileA, const int* __restrict__ tileB,
    const int* __restrict__ Tcnt,
    const float* __restrict__ W_edge, const float* __restrict__ b_edge,
    const float* __restrict__ h, float* __restrict__ out)
{
  const int lane = threadIdx.x & 63;
  const int r16  = lane & 15;
  const int kb   = lane >> 4;
  const int gw   = (int)((blockIdx.x * blockDim.x + threadIdx.x) >> 6);
  const int nw   = (int)((gridDim.x * blockDim.x) >> 6);
  const int T    = Tcnt[0];

  bf16x8 bfr[4][2];
#pragma unroll
  for (int nb = 0; nb < 4; ++nb)
#pragma unroll
    for (int ks = 0; ks < 2; ++ks)
#pragma unroll
      for (int j = 0; j < 8; ++j) {
        const int k = ks * 32 + kb * 8 + j;
        bfr[nb][ks][j] = f2bf(W_edge[k * 64 + nb * 16 + r16]);
      }
  float bb[4];
#pragma unroll
  for (int nb = 0; nb < 4; ++nb) bb[nb] = b_edge[nb * 16 + r16];

  if (gw >= T) return;

  int aC = tileA[gw], stC = tileB[gw];
  bool vC = r16 < (aC >> 20);
  int4 rcC = rec[stC + (vC ? r16 : 0)];
  const float* arC = ef32 + (size_t)(vC ? rcC.y : 0) * 64 + kb * 8;
  f32x4 a0 = *(const f32x4*)(arC);
  f32x4 a1 = *(const f32x4*)(arC + 4);
  f32x4 a2 = *(const f32x4*)(arC + 32);
  f32x4 a3 = *(const f32x4*)(arC + 36);

  for (int ti = gw; ti < T; ti += nw) {
    // ---- issue next tile's loads ----
    const int tn = ti + nw;
    int aN = 0, stN = 0;
    if (tn < T) { aN = tileA[tn]; stN = tileB[tn]; }
    const bool vN = r16 < (aN >> 20);
    const int4 rcN = rec[stN + (vN ? r16 : 0)];
    const float* arN = ef32 + (size_t)(vN ? rcN.y : 0) * 64 + kb * 8;
    const f32x4 n0 = *(const f32x4*)(arN);
    const f32x4 n1 = *(const f32x4*)(arN + 4);
    const f32x4 n2 = *(const f32x4*)(arN + 32);
    const f32x4 n3 = *(const f32x4*)(arN + 36);

    // ---- current tile: MFMA first ----
    const int d  = aC & 0xFFFFF;
    const float wv = vC ? __int_as_float(rcC.z) : 0.0f;
    const int sv = rcC.x;

    bf16x8 af0, af1;
#pragma unroll
    for (int j = 0; j < 4; ++j) {
      af0[j]     = f2bf(a0[j]);
      af0[j + 4] = f2bf(a1[j]);
      af1[j]     = f2bf(a2[j]);
      af1[j + 4] = f2bf(a3[j]);
    }

    f32x4 c[4];
#pragma unroll
    for (int nb = 0; nb < 4; ++nb) c[nb] = (f32x4){0.f, 0.f, 0.f, 0.f};
#pragma unroll
    for (int nb = 0; nb < 4; ++nb) {
      c[nb] = __builtin_amdgcn_mfma_f32_16x16x32_bf16(af0, bfr[nb][0], c[nb], 0, 0, 0);
      c[nb] = __builtin_amdgcn_mfma_f32_16x16x32_bf16(af1, bfr[nb][1], c[nb], 0, 0, 0);
    }

    // ---- epilogue: h gather AFTER MFMAs (shorter live range) ----
    float racc[4] = {0.f, 0.f, 0.f, 0.f};
#pragma unroll
    for (int j = 0; j < 4; ++j) {
      const int row = kb * 4 + j;
      const int sj = __shfl(sv, row, 64);
      const float wj = __shfl(wv, row, 64);
      const float* hrow = h + (size_t)sj * 64 + r16;
#pragma unroll
      for (int nb = 0; nb < 4; ++nb) {
        const float s = c[nb][j] + bb[nb];
        const float p = (1.0f - 2.0f / (__expf(2.0f * s) + 1.0f)) * wj;
        racc[nb] = fmaf(p, hrow[nb * 16], racc[nb]);
      }
    }
#pragma unroll
    for (int nb = 0; nb < 4; ++nb) {
      racc[nb] += __shfl_xor(racc[nb], 16, 64);
      racc[nb] += __shfl_xor(racc[nb], 32, 64);
    }
    float v = racc[0];
    if (kb == 1) v = racc[1];
    if (kb == 2) v = racc[2];
    if (kb == 3) v = racc[3];
    atomicAdd(&out[(size_t)d * 64 + lane], v);

    // ---- rotate pipeline ----
    aC = aN; stC = stN; vC = vN; rcC = rcN;
    a0 = n0; a1 = n1; a2 = n2; a3 = n3;
  }
}

extern "C" void kernel_launch(void* const* d_in, const int* in_sizes, int n_in,
                              void* d_out, int out_size, void* d_ws, size_t ws_size,
                              hipStream_t stream) {
  const float* node_feats   = (const float*)d_in[0];
  const float* edge_feats   = (const float*)d_in[1];
  const float* cond         = (const float*)d_in[2];
  const float* edge_weights = (const float*)d_in[3];
  const int*   src          = (const int*)d_in[4];
  const int*   dst          = (const int*)d_in[5];
  const int*   mirror       = (const int*)d_in[6];
  const float* W_edge       = (const float*)d_in[7];
  const float* b_edge       = (const float*)d_in[8];
  const float* W_cond       = (const float*)d_in[9];
  const float* b_cond       = (const float*)d_in[10];
  const float* W_film       = (const float*)d_in[11];
  const float* b_film       = (const float*)d_in[12];
  const int N = in_sizes[0] / 128;
  const int E = in_sizes[4];
  const int NB = (N + 255) / 256;
  const int Tmax = N + E / 16 + 1;

  char* ws = (char*)d_ws;
  float* h      = (float*)ws;  ws += (size_t)N * 64 * sizeof(float);
  int* cnt      = (int*)ws;    ws += (size_t)((N + 3) & ~3) * sizeof(int);
  int* binst    = (int*)ws;    ws += (size_t)N * sizeof(int);
  int* tileoff  = (int*)ws;    ws += (size_t)N * sizeof(int);
  int* cursor   = (int*)ws;    ws += (size_t)N * sizeof(int);
  int* tileA    = (int*)ws;    ws += (size_t)Tmax * sizeof(int);
  int* tileB    = (int*)ws;    ws += (size_t)Tmax * sizeof(int);
  int* esum     = (int*)ws;    ws += 256 * sizeof(int);
  int* tsum     = (int*)ws;    ws += 256 * sizeof(int);
  int* Tcnt     = (int*)ws;    ws += 320 * sizeof(int);   // pad to 16B boundary
  int4* rec     = (int4*)ws;   ws += (size_t)E * sizeof(int4);

  zero2_kernel<<<512, 256, 0, stream>>>(
      (int4*)cnt, (long long)((N + 3) / 4),
      (int4*)d_out, (long long)(out_size / 4));

  node_hist_kernel<<<2048, 256, 0, stream>>>(
      node_feats, cond, W_cond, b_cond, W_film, b_film, h, N, dst, cnt, E);

  scan_blocks<<<NB, 256, 0, stream>>>(cnt, binst, tileoff, esum, tsum, N);
  scan_tops<<<1, 256, 0, stream>>>(esum, tsum, Tcnt, NB);
  scan_apply_emit<<<NB, 256, 0, stream>>>(binst, tileoff, cursor, esum, tsum,
                                          cnt, tileA, tileB, N);
  fill_kernel<<<1024, 256, 0, stream>>>(dst, src, mirror, edge_weights,
                                        cursor, rec, E);
  gather_tiles_kernel<<<4096, 256, 0, stream>>>(
      edge_feats, rec, tileA, tileB, Tcnt, W_edge, b_edge, h, (float*)d_out);
}

// Round 11
// 256.985 us; speedup vs baseline: 1.3079x; 1.3079x over previous
//
#include <hip/hip_runtime.h>
#include <hip/hip_bf16.h>

#define EPSV 1e-5f

typedef __attribute__((ext_vector_type(8))) short bf16x8;
typedef __attribute__((ext_vector_type(4))) float f32x4;

static __device__ __forceinline__ short f2bf(float f) {
  return __builtin_bit_cast(short, __float2bfloat16(f));
}

// ---------------- custom zero ----------------
__global__ __launch_bounds__(256) void zero2_kernel(
    int4* __restrict__ p1, long long n1,
    int4* __restrict__ p2, long long n2)
{
  const long long stride = (long long)gridDim.x * blockDim.x;
  const int4 z = make_int4(0, 0, 0, 0);
  for (long long i = blockIdx.x * (long long)blockDim.x + threadIdx.x;
       i < n1; i += stride) p1[i] = z;
  for (long long i = blockIdx.x * (long long)blockDim.x + threadIdx.x;
       i < n2; i += stride) p2[i] = z;
}

// ---------------- fused node MFMA + dst histogram ----------------
__global__ __launch_bounds__(256) void node_hist_kernel(
    const float* __restrict__ node_feats, const float* __restrict__ cond,
    const float* __restrict__ W_cond, const float* __restrict__ b_cond,
    const float* __restrict__ W_film, const float* __restrict__ b_film,
    float* __restrict__ h, int N,
    const int* __restrict__ dst, int* __restrict__ cnt, int E)
{
  __shared__ __align__(16) short cond_s[16][264];
  __shared__ __align__(16) short nf_s[16][136];
  __shared__ __align__(16) float gb_s[16][132];
  __shared__ __align__(16) float h_s[16][68];

  const int t = threadIdx.x;

  if (blockIdx.x & 1) {              // ---- hist path ----
    const int vb = (int)(blockIdx.x >> 1);
    const int stride = 1024 * 256;
    for (int e = vb * 256 + t; e < E; e += stride)
      atomicAdd(&cnt[dst[e]], 1);
    return;
  }

  // ---- node path ----
  const int lane = t & 63;
  const int w = t >> 6;
  const int r16 = lane & 15;
  const int kb = lane >> 4;

  const int colc0 = w * 32 + r16;
  const int colc1 = w * 32 + 16 + r16;
  bf16x8 bc[2][8];
#pragma unroll
  for (int ks = 0; ks < 8; ++ks)
#pragma unroll
    for (int j = 0; j < 8; ++j) {
      const int k = ks * 32 + kb * 8 + j;
      bc[0][ks][j] = f2bf(W_cond[k * 128 + colc0]);
      bc[1][ks][j] = f2bf(W_cond[k * 128 + colc1]);
    }
  const int colf = w * 16 + r16;
  bf16x8 bfm[4];
#pragma unroll
  for (int ks = 0; ks < 4; ++ks)
#pragma unroll
    for (int j = 0; j < 8; ++j)
      bfm[ks][j] = f2bf(W_film[(ks * 32 + kb * 8 + j) * 64 + colf]);
  const float bbc0 = b_cond[colc0] + (w < 2 ? 1.0f : 0.0f);
  const float bbc1 = b_cond[colc1] + (w < 2 ? 1.0f : 0.0f);
  const float bbf = b_film[colf];

  const int ntiles = (N + 15) >> 4;
  for (int tile = (int)(blockIdx.x >> 1); tile < ntiles; tile += 1024) {
    const int n0 = tile << 4;
    const int rows = min(16, N - n0);
    {
      const float4* c4 = (const float4*)(cond + (size_t)n0 * 256);
#pragma unroll
      for (int it = 0; it < 4; ++it) {
        const int i = t + it * 256;
        const int row = i >> 6, c = i & 63;
        const float4 v = (row < rows) ? c4[i] : make_float4(0.f, 0.f, 0.f, 0.f);
        short* p = &cond_s[row][c * 4];
        p[0] = f2bf(v.x); p[1] = f2bf(v.y); p[2] = f2bf(v.z); p[3] = f2bf(v.w);
      }
      const float4* n4 = (const float4*)(node_feats + (size_t)n0 * 128);
#pragma unroll
      for (int it = 0; it < 2; ++it) {
        const int i = t + it * 256;
        const int row = i >> 5, c = i & 31;
        const float4 v = (row < rows) ? n4[i] : make_float4(0.f, 0.f, 0.f, 0.f);
        short* p = &nf_s[row][c * 4];
        p[0] = f2bf(v.x); p[1] = f2bf(v.y); p[2] = f2bf(v.z); p[3] = f2bf(v.w);
      }
    }
    __syncthreads();

    f32x4 cg0 = {0.f, 0.f, 0.f, 0.f}, cg1 = {0.f, 0.f, 0.f, 0.f};
#pragma unroll
    for (int ks = 0; ks < 8; ++ks) {
      const bf16x8 a = *(const bf16x8*)&cond_s[r16][ks * 32 + kb * 8];
      cg0 = __builtin_amdgcn_mfma_f32_16x16x32_bf16(a, bc[0][ks], cg0, 0, 0, 0);
      cg1 = __builtin_amdgcn_mfma_f32_16x16x32_bf16(a, bc[1][ks], cg1, 0, 0, 0);
    }
    f32x4 ch = {0.f, 0.f, 0.f, 0.f};
#pragma unroll
    for (int ks = 0; ks < 4; ++ks) {
      const bf16x8 a = *(const bf16x8*)&nf_s[r16][ks * 32 + kb * 8];
      ch = __builtin_amdgcn_mfma_f32_16x16x32_bf16(a, bfm[ks], ch, 0, 0, 0);
    }
#pragma unroll
    for (int j = 0; j < 4; ++j) {
      gb_s[kb * 4 + j][colc0] = cg0[j] + bbc0;
      gb_s[kb * 4 + j][colc1] = cg1[j] + bbc1;
      h_s[kb * 4 + j][colf]   = ch[j] + bbf;
    }
    __syncthreads();

#pragma unroll
    for (int rr = 0; rr < 4; ++rr) {
      const int r = w * 4 + rr;
      const float v = h_s[r][lane];
      float s = v, q = v * v;
#pragma unroll
      for (int off = 1; off < 64; off <<= 1) {
        s += __shfl_xor(s, off, 64);
        q += __shfl_xor(q, off, 64);
      }
      const float mu = s * (1.0f / 64.0f);
      const float var = q * (1.0f / 64.0f) - mu * mu;
      const float hn = (v - mu) * rsqrtf(var + EPSV);
      const float gm = gb_s[r][lane];
      const float bt = gb_s[r][64 + lane];
      if (r < rows)
        h[(size_t)(n0 + r) * 64 + lane] = fmaxf(fmaf(gm, hn, bt), 0.0f);
    }
  }
}

// ---------------- counting-sort scans ----------------
__global__ __launch_bounds__(256) void scan_blocks(
    const int* __restrict__ cnt, int* __restrict__ binst, int* __restrict__ tileoff,
    int* __restrict__ esum, int* __restrict__ tsum, int N)
{
  __shared__ int we[4], wt[4];
  const int t = threadIdx.x, lane = t & 63, w = t >> 6;
  const int i = blockIdx.x * 256 + t;
  const int c  = (i < N) ? cnt[i] : 0;
  const int nt = (c + 15) >> 4;
  int pe = c, pt = nt;
#pragma unroll
  for (int off = 1; off < 64; off <<= 1) {
    const int ae = __shfl_up(pe, off, 64);
    const int at = __shfl_up(pt, off, 64);
    if (lane >= off) { pe += ae; pt += at; }
  }
  if (lane == 63) { we[w] = pe; wt[w] = pt; }
  __syncthreads();
  if (t == 0) {
    int re = 0, rt = 0;
#pragma unroll
    for (int k = 0; k < 4; ++k) { const int a = we[k], b = wt[k]; we[k] = re; wt[k] = rt; re += a; rt += b; }
    esum[blockIdx.x] = re;
    tsum[blockIdx.x] = rt;
  }
  __syncthreads();
  if (i < N) {
    binst[i]   = we[w] + pe - c;
    tileoff[i] = wt[w] + pt - nt;
  }
}

__global__ __launch_bounds__(256) void scan_tops(
    int* __restrict__ esum, int* __restrict__ tsum, int* __restrict__ Tcnt, int NB)
{
  __shared__ int we[4], wt[4];
  const int t = threadIdx.x, lane = t & 63, w = t >> 6;
  const int c  = (t < NB) ? esum[t] : 0;
  const int nt = (t < NB) ? tsum[t] : 0;
  int pe = c, pt = nt;
#pragma unroll
  for (int off = 1; off < 64; off <<= 1) {
    const int ae = __shfl_up(pe, off, 64);
    const int at = __shfl_up(pt, off, 64);
    if (lane >= off) { pe += ae; pt += at; }
  }
  if (lane == 63) { we[w] = pe; wt[w] = pt; }
  __syncthreads();
  if (t == 0) {
    int re = 0, rt = 0;
#pragma unroll
    for (int k = 0; k < 4; ++k) { const int a = we[k], b = wt[k]; we[k] = re; wt[k] = rt; re += a; rt += b; }
    Tcnt[0] = rt;
  }
  __syncthreads();
  if (t < NB) {
    esum[t] = we[w] + pe - c;
    tsum[t] = wt[w] + pt - nt;
  }
}

// scan_apply + emit_tiles fused
__global__ __launch_bounds__(256) void scan_apply_emit(
    int* __restrict__ binst, int* __restrict__ tileoff, int* __restrict__ cursor,
    const int* __restrict__ esum, const int* __restrict__ tsum,
    const int* __restrict__ cnt,
    int* __restrict__ tileA, int* __restrict__ tileB, int N)
{
  const int i = blockIdx.x * 256 + threadIdx.x;
  if (i < N) {
    const int b = binst[i] + esum[blockIdx.x];
    binst[i] = b;
    cursor[i] = b;
    const int to = tileoff[i] + tsum[blockIdx.x];
    tileoff[i] = to;
    const int c = cnt[i];
    const int nt = (c + 15) >> 4;
    for (int k = 0; k < nt; ++k) {
      tileA[to + k] = i | (min(16, c - 16 * k) << 20);
      tileB[to + k] = b + 16 * k;
    }
  }
}

// fill: packed per-slot record {src, mirror, ew_bits, 0}
__global__ __launch_bounds__(256) void fill_kernel(
    const int* __restrict__ dst, const int* __restrict__ src,
    const int* __restrict__ mirror, const float* __restrict__ ew,
    int* __restrict__ cursor, int4* __restrict__ rec, int E)
{
  const int stride = gridDim.x * blockDim.x;
  for (int e = blockIdx.x * blockDim.x + threadIdx.x; e < E; e += stride) {
    const int pos = atomicAdd(&cursor[dst[e]], 1);
    rec[pos] = make_int4(src[e], mirror[e], __float_as_int(ew[e]), 0);
  }
}

// ---------------- fused gather-MFMA-accumulate, depth-1 pipeline -------------
// Pipeline stages the NEXT tile's A-operand as bf16 (8 regs, not 16 f32):
// conversion happens at the rotate point, after the compute phase has covered
// the load latency. No launch_bounds min-waves (R10 lesson: forcing spills).
__global__ __launch_bounds__(256) void gather_tiles_kernel(
    const float* __restrict__ ef32,
    const int4* __restrict__ rec,
    const int* __restrict__ tileA, const int* __restrict__ tileB,
    const int* __restrict__ Tcnt,
    const float* __restrict__ W_edge, const float* __restrict__ b_edge,
    const float* __restrict__ h, float* __restrict__ out)
{
  const int lane = threadIdx.x & 63;
  const int r16  = lane & 15;
  const int kb   = lane >> 4;
  const int gw   = (int)((blockIdx.x * blockDim.x + threadIdx.x) >> 6);
  const int nw   = (int)((gridDim.x * blockDim.x) >> 6);
  const int T    = Tcnt[0];

  bf16x8 bfr[4][2];
#pragma unroll
  for (int nb = 0; nb < 4; ++nb)
#pragma unroll
    for (int ks = 0; ks < 2; ++ks)
#pragma unroll
      for (int j = 0; j < 8; ++j) {
        const int k = ks * 32 + kb * 8 + j;
        bfr[nb][ks][j] = f2bf(W_edge[k * 64 + nb * 16 + r16]);
      }
  float bb[4];
#pragma unroll
  for (int nb = 0; nb < 4; ++nb) bb[nb] = b_edge[nb * 16 + r16];

  if (gw >= T) return;

  // prologue: stage tile gw as bf16 fragments
  int aC = tileA[gw], stC = tileB[gw];
  bool vC = r16 < (aC >> 20);
  int4 rcC = rec[stC + (vC ? r16 : 0)];
  bf16x8 af0P, af1P;
  {
    const float* ar = ef32 + (size_t)(vC ? rcC.y : 0) * 64 + kb * 8;
    const f32x4 t0 = *(const f32x4*)(ar);
    const f32x4 t1 = *(const f32x4*)(ar + 4);
    const f32x4 t2 = *(const f32x4*)(ar + 32);
    const f32x4 t3 = *(const f32x4*)(ar + 36);
#pragma unroll
    for (int j = 0; j < 4; ++j) {
      af0P[j]     = f2bf(t0[j]);
      af0P[j + 4] = f2bf(t1[j]);
      af1P[j]     = f2bf(t2[j]);
      af1P[j + 4] = f2bf(t3[j]);
    }
  }

  for (int ti = gw; ti < T; ti += nw) {
    // ---- issue next tile's loads ----
    const int tn = ti + nw;
    int aN = 0, stN = 0;
    if (tn < T) { aN = tileA[tn]; stN = tileB[tn]; }
    const bool vN = r16 < (aN >> 20);
    const int4 rcN = rec[stN + (vN ? r16 : 0)];
    const float* arN = ef32 + (size_t)(vN ? rcN.y : 0) * 64 + kb * 8;
    const f32x4 n0 = *(const f32x4*)(arN);
    const f32x4 n1 = *(const f32x4*)(arN + 4);
    const f32x4 n2 = *(const f32x4*)(arN + 32);
    const f32x4 n3 = *(const f32x4*)(arN + 36);

    // ---- compute current tile (operands already bf16) ----
    const int d  = aC & 0xFFFFF;
    const float wv = vC ? __int_as_float(rcC.z) : 0.0f;
    const int sv = rcC.x;

    f32x4 c[4];
#pragma unroll
    for (int nb = 0; nb < 4; ++nb) c[nb] = (f32x4){0.f, 0.f, 0.f, 0.f};
#pragma unroll
    for (int nb = 0; nb < 4; ++nb) {
      c[nb] = __builtin_amdgcn_mfma_f32_16x16x32_bf16(af0P, bfr[nb][0], c[nb], 0, 0, 0);
      c[nb] = __builtin_amdgcn_mfma_f32_16x16x32_bf16(af1P, bfr[nb][1], c[nb], 0, 0, 0);
    }

    // ---- epilogue: h gather after MFMAs ----
    float racc[4] = {0.f, 0.f, 0.f, 0.f};
#pragma unroll
    for (int j = 0; j < 4; ++j) {
      const int row = kb * 4 + j;
      const int sj = __shfl(sv, row, 64);
      const float wj = __shfl(wv, row, 64);
      const float* hrow = h + (size_t)sj * 64 + r16;
#pragma unroll
      for (int nb = 0; nb < 4; ++nb) {
        const float s = c[nb][j] + bb[nb];
        const float p = (1.0f - 2.0f / (__expf(2.0f * s) + 1.0f)) * wj;
        racc[nb] = fmaf(p, hrow[nb * 16], racc[nb]);
      }
    }
#pragma unroll
    for (int nb = 0; nb < 4; ++nb) {
      racc[nb] += __shfl_xor(racc[nb], 16, 64);
      racc[nb] += __shfl_xor(racc[nb], 32, 64);
    }
    float v = racc[0];
    if (kb == 1) v = racc[1];
    if (kb == 2) v = racc[2];
    if (kb == 3) v = racc[3];
    atomicAdd(&out[(size_t)d * 64 + lane], v);

    // ---- rotate: convert next tile's A to bf16 (loads have landed) ----
#pragma unroll
    for (int j = 0; j < 4; ++j) {
      af0P[j]     = f2bf(n0[j]);
      af0P[j + 4] = f2bf(n1[j]);
      af1P[j]     = f2bf(n2[j]);
      af1P[j + 4] = f2bf(n3[j]);
    }
    aC = aN; stC = stN; vC = vN; rcC = rcN;
  }
}

extern "C" void kernel_launch(void* const* d_in, const int* in_sizes, int n_in,
                              void* d_out, int out_size, void* d_ws, size_t ws_size,
                              hipStream_t stream) {
  const float* node_feats   = (const float*)d_in[0];
  const float* edge_feats   = (const float*)d_in[1];
  const float* cond         = (const float*)d_in[2];
  const float* edge_weights = (const float*)d_in[3];
  const int*   src          = (const int*)d_in[4];
  const int*   dst          = (const int*)d_in[5];
  const int*   mirror       = (const int*)d_in[6];
  const float* W_edge       = (const float*)d_in[7];
  const float* b_edge       = (const float*)d_in[8];
  const float* W_cond       = (const float*)d_in[9];
  const float* b_cond       = (const float*)d_in[10];
  const float* W_film       = (const float*)d_in[11];
  const float* b_film       = (const float*)d_in[12];
  const int N = in_sizes[0] / 128;
  const int E = in_sizes[4];
  const int NB = (N + 255) / 256;
  const int Tmax = N + E / 16 + 1;

  char* ws = (char*)d_ws;
  float* h      = (float*)ws;  ws += (size_t)N * 64 * sizeof(float);
  int* cnt      = (int*)ws;    ws += (size_t)((N + 3) & ~3) * sizeof(int);
  int* binst    = (int*)ws;    ws += (size_t)N * sizeof(int);
  int* tileoff  = (int*)ws;    ws += (size_t)N * sizeof(int);
  int* cursor   = (int*)ws;    ws += (size_t)N * sizeof(int);
  int* tileA    = (int*)ws;    ws += (size_t)Tmax * sizeof(int);
  int* tileB    = (int*)ws;    ws += (size_t)Tmax * sizeof(int);
  int* esum     = (int*)ws;    ws += 256 * sizeof(int);
  int* tsum     = (int*)ws;    ws += 256 * sizeof(int);
  int* Tcnt     = (int*)ws;    ws += 320 * sizeof(int);   // pad to 16B boundary
  int4* rec     = (int4*)ws;   ws += (size_t)E * sizeof(int4);

  zero2_kernel<<<512, 256, 0, stream>>>(
      (int4*)cnt, (long long)((N + 3) / 4),
      (int4*)d_out, (long long)(out_size / 4));

  node_hist_kernel<<<2048, 256, 0, stream>>>(
      node_feats, cond, W_cond, b_cond, W_film, b_film, h, N, dst, cnt, E);

  scan_blocks<<<NB, 256, 0, stream>>>(cnt, binst, tileoff, esum, tsum, N);
  scan_tops<<<1, 256, 0, stream>>>(esum, tsum, Tcnt, NB);
  scan_apply_emit<<<NB, 256, 0, stream>>>(binst, tileoff, cursor, esum, tsum,
                                          cnt, tileA, tileB, N);
  fill_kernel<<<1024, 256, 0, stream>>>(dst, src, mirror, edge_weights,
                                        cursor, rec, E);
  gather_tiles_kernel<<<4096, 256, 0, stream>>>(
      edge_feats, rec, tileA, tileB, Tcnt, W_edge, b_edge, h, (float*)d_out);
}